// Round 5
// baseline (233.779 us; speedup 1.0000x reference)
//
#include <hip/hip_runtime.h>
#include <hip/hip_fp16.h>

// GCNRegressor: x[n,128] --GCNConv(W1)--> relu --GCNConv(W2)--> relu --@Wl+bl--> out[n]
// n=100000, E=1600000, IN=128, HID=64.
// R1-R10: CSR+gather, counting sort, fp16 features, MFMA GEMMs: 2913 -> 171 us.
// R11: 8-rows-per-VMEM gather (wave = 8 groups x 8 lanes, uint4/lane): 41.8us agg.
// R12/R13: dot2 + fewer slots: VALU -25% but dur +3..15%. LESSON: agg is
//      LATENCY-bound; issue all loads back-to-back, no branches in between.
// R14: 2 nodes per wave, software-pipelined (16 VMEM in flight): 162 -> 148.7.
// R15: fixed 32-slot cfix (dummy baked in) + 4 nodes/wave (32 VMEM in flight).
//      Aggs fine, but k_bin exposed at 40us (LDS-atomic bound, 8% of HBM peak)
//      + k_bfill heavier: 148.7 -> 156.9.
// R16: kill the counting sort entirely. Direct global-atomic scatter into cfix
//      (1.6M atomics over 100K counters, ~16/counter): k_bin+k_bfill+binned ->
//      memset + k_scatter + k_post. Dummy re-encoded as row 0 (features shifted
//      up one row; zero-filled cfix slots hit the zero row), so the dummy
//      prefill is ONE hipMemsetAsync. deg>32 overflow -> tiny global append
//      list, scanned by the rare agg tail.

#define SLOTS 32
#define OVCAP 8192

using f16x8 = __attribute__((ext_vector_type(8))) _Float16;
using f16x2 = __attribute__((ext_vector_type(2))) _Float16;
using f32x4 = __attribute__((ext_vector_type(4))) float;

// ---- CSR build: direct scatter. cfix[d*32+off] = (src+1)<<7 (byte offset of
// src row in hs, which has the zero dummy row at index 0). Overflow edges
// (off>=32, ~50 globally) append (d, rowoff) to ovlist. Block 0 also zeroes
// hs row 0. ----
__global__ __launch_bounds__(256) void k_scatter(const int* __restrict__ src,
                                                 const int* __restrict__ dst,
                                                 int* __restrict__ cnt,
                                                 int* __restrict__ cfix,
                                                 int* __restrict__ ovlist,
                                                 int* __restrict__ ovn,
                                                 __half* __restrict__ hs, int E) {
    if (blockIdx.x == 0 && threadIdx.x < 8) {
        uint4 z = {0u, 0u, 0u, 0u};
        reinterpret_cast<uint4*>(hs)[threadIdx.x] = z;   // zero dummy row 0
    }
    const int e4 = (blockIdx.x * 256 + threadIdx.x) * 4;
    if (e4 >= E) return;
    const int4 d4 = *reinterpret_cast<const int4*>(dst + e4);
    const int4 s4 = *reinterpret_cast<const int4*>(src + e4);
    // 4 independent atomic+store chains (different d in general -> all in flight)
    int o0 = atomicAdd(&cnt[d4.x], 1);
    int o1 = atomicAdd(&cnt[d4.y], 1);
    int o2 = atomicAdd(&cnt[d4.z], 1);
    int o3 = atomicAdd(&cnt[d4.w], 1);
    int v0 = (s4.x + 1) << 7;
    int v1 = (s4.y + 1) << 7;
    int v2 = (s4.z + 1) << 7;
    int v3 = (s4.w + 1) << 7;
    if (o0 < SLOTS) cfix[d4.x * SLOTS + o0] = v0;
    else { int oi = atomicAdd(ovn, 1); if (oi < OVCAP) { ovlist[2*oi] = d4.x; ovlist[2*oi+1] = v0; } }
    if (o1 < SLOTS) cfix[d4.y * SLOTS + o1] = v1;
    else { int oi = atomicAdd(ovn, 1); if (oi < OVCAP) { ovlist[2*oi] = d4.y; ovlist[2*oi+1] = v1; } }
    if (o2 < SLOTS) cfix[d4.z * SLOTS + o2] = v2;
    else { int oi = atomicAdd(ovn, 1); if (oi < OVCAP) { ovlist[2*oi] = d4.z; ovlist[2*oi+1] = v2; } }
    if (o3 < SLOTS) cfix[d4.w * SLOTS + o3] = v3;
    else { int oi = atomicAdd(ovn, 1); if (oi < OVCAP) { ovlist[2*oi] = d4.w; ovlist[2*oi+1] = v3; } }
}

// ---- per-node finalize: dinv + capped deg byte ----
__global__ __launch_bounds__(256) void k_post(const int* __restrict__ cnt,
                                              float* __restrict__ dinv,
                                              unsigned char* __restrict__ degc,
                                              int n) {
    const int i = blockIdx.x * 256 + threadIdx.x;
    if (i >= n) return;
    const int dg = cnt[i];
    dinv[i] = rsqrtf((float)dg + 1.0f);
    degc[i] = (unsigned char)min(dg, 255);
}

// MFMA GEMM: C16[row,64] = fp16( (A[row,K] @ W[K,64]) * dinv[row] ).
// Block = 256 threads = 4 waves; wave w computes rows rb+w*16..+15, all 64 cols.
template <int K, bool A_FP32>
__global__ __launch_bounds__(256) void k_gemm_mfma(const void* __restrict__ Av,
                                                   const float* __restrict__ W,
                                                   const float* __restrict__ dinv,
                                                   __half* __restrict__ C, int n) {
    constexpr int KP = K + 8;  // padded LDS row stride in halves (16B aligned)
    __shared__ _Float16 Wt[64 * KP];
    const int tid = threadIdx.x;
    for (int i = tid; i < K * 64; i += 256) {
        int k = i >> 6, c = i & 63;
        Wt[c * KP + k] = (_Float16)W[i];
    }
    __syncthreads();

    const int lane = tid & 63;
    const int wv = tid >> 6;
    const int r16 = lane & 15;
    const int kq = lane >> 4;                       // 0..3
    const int rb = blockIdx.x * 64 + wv * 16;
    const int arow = min(rb + r16, n - 1);          // clamped A row for this lane

    f32x4 acc[4] = {{0.f,0.f,0.f,0.f},{0.f,0.f,0.f,0.f},
                    {0.f,0.f,0.f,0.f},{0.f,0.f,0.f,0.f}};

#pragma unroll
    for (int kk = 0; kk < K; kk += 32) {
        f16x8 a;
        if (A_FP32) {
            const float* Ap = (const float*)Av + (size_t)arow * K + kk + kq * 8;
            float4 f0 = *reinterpret_cast<const float4*>(Ap);
            float4 f1 = *reinterpret_cast<const float4*>(Ap + 4);
            a[0] = (_Float16)f0.x; a[1] = (_Float16)f0.y;
            a[2] = (_Float16)f0.z; a[3] = (_Float16)f0.w;
            a[4] = (_Float16)f1.x; a[5] = (_Float16)f1.y;
            a[6] = (_Float16)f1.z; a[7] = (_Float16)f1.w;
        } else {
            const _Float16* Ap = (const _Float16*)Av + (size_t)arow * K + kk + kq * 8;
            a = *reinterpret_cast<const f16x8*>(Ap);
        }
#pragma unroll
        for (int nt = 0; nt < 4; ++nt) {
            f16x8 b = *reinterpret_cast<const f16x8*>(&Wt[(nt * 16 + r16) * KP + kk + kq * 8]);
            acc[nt] = __builtin_amdgcn_mfma_f32_16x16x32_f16(a, b, acc[nt], 0, 0, 0);
        }
    }

#pragma unroll
    for (int r = 0; r < 4; ++r) {
        const int row = rb + kq * 4 + r;
        if (row < n) {
            const float di = dinv[row];
#pragma unroll
            for (int nt = 0; nt < 4; ++nt)
                C[((size_t)row << 6) + nt * 16 + r16] = __float2half(acc[nt][r] * di);
        }
    }
}

// Accumulate 8 fp16 (one uint4) into acc[8] via v_dot2_f32_f16: one VALU op per
// value (convert+add fused, fp32 accumulate). Masks (1,0)/(0,1) keep channels
// separate; exact 1.0-multiply => bit-identical to cvt+add.
__device__ __forceinline__ void dotu4(float acc[8], uint4 u, f16x2 pl, f16x2 ph) {
    union { uint4 u4; f16x2 h[4]; } v;
    v.u4 = u;
    acc[0] = __builtin_amdgcn_fdot2(v.h[0], pl, acc[0], false);
    acc[1] = __builtin_amdgcn_fdot2(v.h[0], ph, acc[1], false);
    acc[2] = __builtin_amdgcn_fdot2(v.h[1], pl, acc[2], false);
    acc[3] = __builtin_amdgcn_fdot2(v.h[1], ph, acc[3], false);
    acc[4] = __builtin_amdgcn_fdot2(v.h[2], pl, acc[4], false);
    acc[5] = __builtin_amdgcn_fdot2(v.h[2], ph, acc[5], false);
    acc[6] = __builtin_amdgcn_fdot2(v.h[3], pl, acc[6], false);
    acc[7] = __builtin_amdgcn_fdot2(v.h[3], ph, acc[7], false);
}

// Fold partial sums across the 8 groups: after this every lane holds the full
// sums for its channel-slice p.
__device__ __forceinline__ void fold8(float acc[8]) {
#pragma unroll
    for (int m = 8; m <= 32; m <<= 1) {
#pragma unroll
        for (int j = 0; j < 8; ++j)
            acc[j] += __shfl_xor(acc[j], m, 64);
    }
}

// 4-node pipelined gather. Wave = 8 groups x 8 lanes; each group's uint4 load
// fetches one full 128B row. cfix addresses are pure arithmetic: ALL 16 colidx
// loads then ALL 16 gather uint4s issue back-to-back (32 VMEM in flight). No
// masking -- zero-filled cfix slots hit the zero dummy row 0 of hs.
__device__ __forceinline__ void gather_quad(const char* __restrict__ hsb,
                                            const int* __restrict__ cfix,
                                            int ic0, int ic1, int ic2, int ic3,
                                            int g, int p,
                                            float a0[8], float a1[8],
                                            float a2[8], float a3[8]) {
    const f16x2 pl = {(_Float16)1.0f, (_Float16)0.0f};
    const f16x2 ph = {(_Float16)0.0f, (_Float16)1.0f};
    const unsigned poff = (unsigned)(p << 4);
    const int b0 = ic0 * SLOTS + g;
    const int b1 = ic1 * SLOTS + g;
    const int b2 = ic2 * SLOTS + g;
    const int b3 = ic3 * SLOTS + g;
    // --- 16 colidx loads (addresses known at wave start) ---
    unsigned oa0 = (unsigned)cfix[b0]      + poff;
    unsigned oa1 = (unsigned)cfix[b0 + 8]  + poff;
    unsigned oa2 = (unsigned)cfix[b0 + 16] + poff;
    unsigned oa3 = (unsigned)cfix[b0 + 24] + poff;
    unsigned ob0 = (unsigned)cfix[b1]      + poff;
    unsigned ob1 = (unsigned)cfix[b1 + 8]  + poff;
    unsigned ob2 = (unsigned)cfix[b1 + 16] + poff;
    unsigned ob3 = (unsigned)cfix[b1 + 24] + poff;
    unsigned oc0 = (unsigned)cfix[b2]      + poff;
    unsigned oc1 = (unsigned)cfix[b2 + 8]  + poff;
    unsigned oc2 = (unsigned)cfix[b2 + 16] + poff;
    unsigned oc3 = (unsigned)cfix[b2 + 24] + poff;
    unsigned od0 = (unsigned)cfix[b3]      + poff;
    unsigned od1 = (unsigned)cfix[b3 + 8]  + poff;
    unsigned od2 = (unsigned)cfix[b3 + 16] + poff;
    unsigned od3 = (unsigned)cfix[b3 + 24] + poff;
    // --- 16 gathers ---
    uint4 ua0 = *reinterpret_cast<const uint4*>(hsb + oa0);
    uint4 ua1 = *reinterpret_cast<const uint4*>(hsb + oa1);
    uint4 ua2 = *reinterpret_cast<const uint4*>(hsb + oa2);
    uint4 ua3 = *reinterpret_cast<const uint4*>(hsb + oa3);
    uint4 ub0 = *reinterpret_cast<const uint4*>(hsb + ob0);
    uint4 ub1 = *reinterpret_cast<const uint4*>(hsb + ob1);
    uint4 ub2 = *reinterpret_cast<const uint4*>(hsb + ob2);
    uint4 ub3 = *reinterpret_cast<const uint4*>(hsb + ob3);
    uint4 uc0 = *reinterpret_cast<const uint4*>(hsb + oc0);
    uint4 uc1 = *reinterpret_cast<const uint4*>(hsb + oc1);
    uint4 uc2 = *reinterpret_cast<const uint4*>(hsb + oc2);
    uint4 uc3 = *reinterpret_cast<const uint4*>(hsb + oc3);
    uint4 ud0 = *reinterpret_cast<const uint4*>(hsb + od0);
    uint4 ud1 = *reinterpret_cast<const uint4*>(hsb + od1);
    uint4 ud2 = *reinterpret_cast<const uint4*>(hsb + od2);
    uint4 ud3 = *reinterpret_cast<const uint4*>(hsb + od3);
    // --- consume in order; later nodes' loads still in flight ---
    dotu4(a0, ua0, pl, ph);
    dotu4(a0, ua1, pl, ph);
    dotu4(a0, ua2, pl, ph);
    dotu4(a0, ua3, pl, ph);
    dotu4(a1, ub0, pl, ph);
    dotu4(a1, ub1, pl, ph);
    dotu4(a1, ub2, pl, ph);
    dotu4(a1, ub3, pl, ph);
    dotu4(a2, uc0, pl, ph);
    dotu4(a2, uc1, pl, ph);
    dotu4(a2, uc2, pl, ph);
    dotu4(a2, uc3, pl, ph);
    dotu4(a3, ud0, pl, ph);
    dotu4(a3, ud1, pl, ph);
    dotu4(a3, ud2, pl, ph);
    dotu4(a3, ud3, pl, ph);
}

// Rare tail (any deg>32 in the quad): scan the global overflow list (~tens of
// entries). Only group 0 contributes (fold8 sums groups).
__device__ __forceinline__ void tail_scan(const char* __restrict__ hsb,
                                          const int* __restrict__ ovlist, int K,
                                          int ic0, int ic1, int ic2, int ic3,
                                          int g, int p,
                                          float a0[8], float a1[8],
                                          float a2[8], float a3[8]) {
    if (g != 0) return;
    const f16x2 pl = {(_Float16)1.0f, (_Float16)0.0f};
    const f16x2 ph = {(_Float16)0.0f, (_Float16)1.0f};
    const unsigned poff = (unsigned)(p << 4);
    for (int j = 0; j < K; ++j) {
        int d = ovlist[2 * j];
        if (d != ic0 && d != ic1 && d != ic2 && d != ic3) continue;
        unsigned v = (unsigned)ovlist[2 * j + 1] + poff;
        uint4 u = *reinterpret_cast<const uint4*>(hsb + v);
        if (d == ic0) dotu4(a0, u, pl, ph);
        else if (d == ic1) dotu4(a1, u, pl, ph);
        else if (d == ic2) dotu4(a2, u, pl, ph);
        else dotu4(a3, u, pl, ph);
    }
}

// Select this lane's node accumulator (nsel in 0..3) -- 16 cndmasks, once/wave.
__device__ __forceinline__ void sel4(float a[8], int nsel, const float a0[8],
                                     const float a1[8], const float a2[8],
                                     const float a3[8]) {
#pragma unroll
    for (int j = 0; j < 8; ++j) {
        float x01 = (nsel & 1) ? a1[j] : a0[j];
        float x23 = (nsel & 1) ? a3[j] : a2[j];
        a[j] = (nsel & 2) ? x23 : x01;
    }
}

// conv1 aggregation: out16 = fp16(relu(di*(sum_e hs[src_e] + hs_i) + b)).
// 4 nodes per wave; epilogue: lane group g (g<4) finalizes node i0+g.
// hs has the zero dummy row at index 0; node i lives at row i+1.
__global__ __launch_bounds__(256) void k_agg_relu(const __half* __restrict__ hs,
                                                  const int* __restrict__ cfix,
                                                  const unsigned char* __restrict__ degc,
                                                  const int* __restrict__ ovlist,
                                                  const int* __restrict__ ovn,
                                                  const float* __restrict__ dinv,
                                                  const float* __restrict__ b,
                                                  __half* __restrict__ out, int n) {
    const int wv = threadIdx.x >> 6;
    const int i0 = blockIdx.x * 16 + wv * 4;
    const int lane = threadIdx.x & 63;
    if (i0 >= n) return;
    const int g = lane >> 3, p = lane & 7;
    const int ic0 = i0;
    const int ic1 = min(i0 + 1, n - 1);
    const int ic2 = min(i0 + 2, n - 1);
    const int ic3 = min(i0 + 3, n - 1);
    const int nsel = g & 3;
    const int it = i0 + nsel;              // unclamped, for store guard
    const int iw = min(it, n - 1);
    // hoisted independent loads (off critical path)
    uint4 su = *reinterpret_cast<const uint4*>(hs + (((size_t)iw + 1) << 6) + (p << 3));
    const float di = dinv[iw];
    float a0[8] = {}, a1[8] = {}, a2[8] = {}, a3[8] = {};
    gather_quad((const char*)hs, cfix, ic0, ic1, ic2, ic3, g, p, a0, a1, a2, a3);
    const int dmax = max(max((int)degc[ic0], (int)degc[ic1]),
                         max((int)degc[ic2], (int)degc[ic3]));
    if (dmax > SLOTS) {
        int K = min(ovn[0], OVCAP);
        tail_scan((const char*)hs, ovlist, K, ic0, ic1, ic2, ic3, g, p,
                  a0, a1, a2, a3);
    }
    fold8(a0);
    fold8(a1);
    fold8(a2);
    fold8(a3);
    if (lane < 32 && it < n) {
        const f16x2 pl = {(_Float16)1.0f, (_Float16)0.0f};
        const f16x2 ph = {(_Float16)0.0f, (_Float16)1.0f};
        float a[8];
        sel4(a, nsel, a0, a1, a2, a3);
        dotu4(a, su, pl, ph);
        float4 b0 = *reinterpret_cast<const float4*>(b + (p << 3));
        float4 b1 = *reinterpret_cast<const float4*>(b + (p << 3) + 4);
        __half2 h0 = __halves2half2(__float2half(fmaxf(fmaf(a[0], di, b0.x), 0.f)),
                                    __float2half(fmaxf(fmaf(a[1], di, b0.y), 0.f)));
        __half2 h1 = __halves2half2(__float2half(fmaxf(fmaf(a[2], di, b0.z), 0.f)),
                                    __float2half(fmaxf(fmaf(a[3], di, b0.w), 0.f)));
        __half2 h2 = __halves2half2(__float2half(fmaxf(fmaf(a[4], di, b1.x), 0.f)),
                                    __float2half(fmaxf(fmaf(a[5], di, b1.y), 0.f)));
        __half2 h3 = __halves2half2(__float2half(fmaxf(fmaf(a[6], di, b1.z), 0.f)),
                                    __float2half(fmaxf(fmaf(a[7], di, b1.w), 0.f)));
        uint4 u;
        u.x = *reinterpret_cast<unsigned*>(&h0);
        u.y = *reinterpret_cast<unsigned*>(&h1);
        u.z = *reinterpret_cast<unsigned*>(&h2);
        u.w = *reinterpret_cast<unsigned*>(&h3);
        *reinterpret_cast<uint4*>(out + ((size_t)it << 6) + (p << 3)) = u;
    }
}

// conv2 aggregation + relu + (.@Wl + bl) head, fused. 4 nodes per wave;
// group g handles node i0+(g&3) (groups 4-7 redundant); xor-1,2,4 reduce stays
// within each 8-lane group; lane of p==0, g<4 stores node i0+g.
__global__ __launch_bounds__(256) void k_agg_head(const __half* __restrict__ hs,
                                                  const int* __restrict__ cfix,
                                                  const unsigned char* __restrict__ degc,
                                                  const int* __restrict__ ovlist,
                                                  const int* __restrict__ ovn,
                                                  const float* __restrict__ dinv,
                                                  const float* __restrict__ b2,
                                                  const float* __restrict__ Wl,
                                                  const float* __restrict__ bl,
                                                  float* __restrict__ out, int n) {
    const int wv = threadIdx.x >> 6;
    const int i0 = blockIdx.x * 16 + wv * 4;
    const int lane = threadIdx.x & 63;
    if (i0 >= n) return;
    const int g = lane >> 3, p = lane & 7;
    const int ic0 = i0;
    const int ic1 = min(i0 + 1, n - 1);
    const int ic2 = min(i0 + 2, n - 1);
    const int ic3 = min(i0 + 3, n - 1);
    const int nsel = g & 3;
    const int it = i0 + nsel;
    const int iw = min(it, n - 1);
    uint4 su = *reinterpret_cast<const uint4*>(hs + (((size_t)iw + 1) << 6) + (p << 3));
    const float di = dinv[iw];
    float a0[8] = {}, a1[8] = {}, a2[8] = {}, a3[8] = {};
    gather_quad((const char*)hs, cfix, ic0, ic1, ic2, ic3, g, p, a0, a1, a2, a3);
    const int dmax = max(max((int)degc[ic0], (int)degc[ic1]),
                         max((int)degc[ic2], (int)degc[ic3]));
    if (dmax > SLOTS) {
        int K = min(ovn[0], OVCAP);
        tail_scan((const char*)hs, ovlist, K, ic0, ic1, ic2, ic3, g, p,
                  a0, a1, a2, a3);
    }
    fold8(a0);
    fold8(a1);
    fold8(a2);
    fold8(a3);
    const f16x2 pl = {(_Float16)1.0f, (_Float16)0.0f};
    const f16x2 ph = {(_Float16)0.0f, (_Float16)1.0f};
    float a[8];
    sel4(a, nsel, a0, a1, a2, a3);
    dotu4(a, su, pl, ph);
    float4 b0 = *reinterpret_cast<const float4*>(b2 + (p << 3));
    float4 b1 = *reinterpret_cast<const float4*>(b2 + (p << 3) + 4);
    float4 w0 = *reinterpret_cast<const float4*>(Wl + (p << 3));
    float4 w1 = *reinterpret_cast<const float4*>(Wl + (p << 3) + 4);
    float v = fmaxf(fmaf(a[0], di, b0.x), 0.f) * w0.x
            + fmaxf(fmaf(a[1], di, b0.y), 0.f) * w0.y
            + fmaxf(fmaf(a[2], di, b0.z), 0.f) * w0.z
            + fmaxf(fmaf(a[3], di, b0.w), 0.f) * w0.w
            + fmaxf(fmaf(a[4], di, b1.x), 0.f) * w1.x
            + fmaxf(fmaf(a[5], di, b1.y), 0.f) * w1.y
            + fmaxf(fmaf(a[6], di, b1.z), 0.f) * w1.z
            + fmaxf(fmaf(a[7], di, b1.w), 0.f) * w1.w;
    v += __shfl_xor(v, 1, 64);
    v += __shfl_xor(v, 2, 64);
    v += __shfl_xor(v, 4, 64);
    if (p == 0 && g < 4 && it < n) out[it] = v + bl[0];
}

extern "C" void kernel_launch(void* const* d_in, const int* in_sizes, int n_in,
                              void* d_out, int out_size, void* d_ws, size_t ws_size,
                              hipStream_t stream) {
    const float* x  = (const float*)d_in[0];
    const int*   ei = (const int*)d_in[1];
    const float* W1 = (const float*)d_in[2];
    const float* b1 = (const float*)d_in[3];
    const float* W2 = (const float*)d_in[4];
    const float* b2 = (const float*)d_in[5];
    const float* Wl = (const float*)d_in[6];
    const float* bl = (const float*)d_in[7];
    float* out = (float*)d_out;

    const int n = in_sizes[0] / 128;   // 100000
    const int E = in_sizes[1] / 2;     // 1600000
    const int* src = ei;
    const int* dst = ei + E;

    char* ws = (char*)d_ws;
    size_t o = 0;
    auto alloc = [&](size_t bytes) {
        void* p = ws + o;
        o = (o + bytes + 255) & ~(size_t)255;
        return p;
    };
    // zeroed region (one memset): cnt | ovn | cfix
    int*   cnt  = (int*)alloc((size_t)n * 4);
    int*   ovn  = (int*)alloc(256);
    int*   cfix = (int*)alloc((size_t)n * SLOTS * 4);
    size_t zbytes = (size_t)((char*)cfix + (size_t)n * SLOTS * 4 - (char*)cnt);
    // non-zeroed
    int*   ovlist = (int*)alloc((size_t)OVCAP * 2 * 4);
    float* dinv   = (float*)alloc((size_t)n * 4);
    unsigned char* degc = (unsigned char*)alloc((size_t)n);
    __half* hs    = (__half*)alloc((size_t)(n + 1) * 64 * 2);  // row 0 = zero dummy
    __half* bufA  = (__half*)alloc((size_t)n * 64 * 2);        // fp16 relu output

    // ---- CSR build: memset + direct scatter + per-node finalize ----
    hipMemsetAsync(cnt, 0, zbytes, stream);
    k_scatter<<<(E / 4 + 255) / 256, 256, 0, stream>>>(src, dst, cnt, cfix,
                                                       ovlist, ovn, hs, E);
    k_post<<<(n + 255) / 256, 256, 0, stream>>>(cnt, dinv, degc, n);

    // ---- conv1 ----  (GEMM writes node i at hs row i+1)
    k_gemm_mfma<128, true><<<(n + 63) / 64, 256, 0, stream>>>(x, W1, dinv, hs + 64, n);
    k_agg_relu<<<(n + 15) / 16, 256, 0, stream>>>(hs, cfix, degc, ovlist, ovn,
                                                  dinv, b1, bufA, n);

    // ---- conv2 + head ----
    k_gemm_mfma<64, false><<<(n + 63) / 64, 256, 0, stream>>>(bufA, W2, dinv, hs + 64, n);
    k_agg_head<<<(n + 15) / 16, 256, 0, stream>>>(hs, cfix, degc, ovlist, ovn,
                                                  dinv, b2, Wl, bl, out, n);
}

// Round 6
// 166.605 us; speedup vs baseline: 1.4032x; 1.4032x over previous
//
#include <hip/hip_runtime.h>
#include <hip/hip_fp16.h>

// GCNRegressor: x[n,128] --GCNConv(W1)--> relu --GCNConv(W2)--> relu --@Wl+bl--> out[n]
// n=100000, E=1600000, IN=128, HID=64.
// R1-R10: CSR+gather, counting sort, fp16 features, MFMA GEMMs: 2913 -> 171 us.
// R11: 8-rows-per-VMEM gather (wave = 8 groups x 8 lanes, uint4/lane): 41.8us agg.
// R12/R13: dot2 + fewer slots: VALU -25% but dur +3..15%. LESSON: agg is
//      LATENCY-bound; issue all loads back-to-back, no branches in between.
// R14: 2 nodes per wave, software-pipelined (16 VMEM in flight): 162 -> 148.7. BEST.
// R15: fixed-slot cfix + 4 nodes/wave: aggs ok but k_bin exposed at 40us
//      (LDS-atomic serialization, 23% occupancy) + heavier k_bfill: 156.9.
// R16: direct global-atomic scatter: 15x WRITE amplification (96MB for 13MB,
//      4B random stores never coalesce, lines bounce across XCDs): 233.8.
//      LESSON: scatter must stay block-local (L2-resident until lines fill).
// R17: R14 structure verbatim (aggs untouched) + de-serialized CSR build:
//      wave-private LDS histograms (contention /4, base baked into cursors at
//      merge), BIN_CH 1024 (2x blocks), SHIFT 8 (391 buckets: k_bfill gets 391
//      blocks + 1 node/thread; k_bin per-address contention halved again).

#define SHIFT 8
#define BSZ   (1 << SHIFT)     // 256 nodes per bucket
#define NBMAX 512              // >= nb = 391
#define BIN_CH 1024
#define BCAP  6144             // per-bucket capacity (mean 4092, 1.5x slack)

using f16x8 = __attribute__((ext_vector_type(8))) _Float16;
using f16x2 = __attribute__((ext_vector_type(2))) _Float16;
using f32x4 = __attribute__((ext_vector_type(4))) float;

// ---- Phase 1: bin edges into fixed-capacity buckets; bcursor = counts ----
// Wave-private histograms: hist and place both go through h[wave][bucket];
// merge folds the 4 copies, reserves the block's range from bcursor once, and
// rewrites h as ABSOLUTE per-wave cursors (base baked in). pack: src(17b) |
// local_node(8b)<<17. Block 0 also zeroes the dummy hs row (index n).
__global__ __launch_bounds__(256) void k_bin(const int* __restrict__ src,
                                             const int* __restrict__ dst,
                                             int* __restrict__ bcursor,
                                             unsigned* __restrict__ binned,
                                             __half* __restrict__ hs, int n, int E) {
    if (blockIdx.x == 0 && threadIdx.x < 8) {
        uint4 z = {0u, 0u, 0u, 0u};
        reinterpret_cast<uint4*>(hs + ((size_t)n << 6))[threadIdx.x] = z;
    }
    __shared__ int h[4][NBMAX];   // 8 KB
    const int t = threadIdx.x;
    const int wv = t >> 6;
    const int beg = blockIdx.x * BIN_CH;
    const int end = min(beg + BIN_CH, E);
    for (int i = t; i < 4 * NBMAX; i += 256) (&h[0][0])[i] = 0;
    __syncthreads();
    for (int e = beg + t; e < end; e += 256)
        atomicAdd(&h[wv][dst[e] >> SHIFT], 1);
    __syncthreads();
    for (int i = t; i < NBMAX; i += 256) {
        int c0 = h[0][i], c1 = h[1][i], c2 = h[2][i], c3 = h[3][i];
        int tot = c0 + c1 + c2 + c3;
        int gb = tot ? atomicAdd(&bcursor[i], tot) : 0;
        h[0][i] = gb;
        h[1][i] = gb + c0;
        h[2][i] = gb + c0 + c1;
        h[3][i] = gb + c0 + c1 + c2;
    }
    __syncthreads();
    for (int e = beg + t; e < end; e += 256) {
        int d = dst[e];
        int b = d >> SHIFT;
        int off = atomicAdd(&h[wv][b], 1);   // absolute offset within bucket
        binned[(size_t)b * BCAP + off] =
            (unsigned)src[e] | ((unsigned)(d & (BSZ - 1)) << 17);
    }
}

// ---- Phase 2: per-bucket count + scan + packed rowptr + place ----
// BSZ=256 -> exactly one node per thread. Wave-private count/place cursors.
// rowptr[g] = (edge_base << 8) | min(deg,255) ; colidx entry = src_byte_off.
__global__ __launch_bounds__(256) void k_bfill(const unsigned* __restrict__ binned,
                                               const int* __restrict__ counts,
                                               int* __restrict__ rowptr,
                                               int* __restrict__ colidx,
                                               float* __restrict__ dinv, int n) {
    __shared__ int c[4][BSZ];    // 4 KB
    __shared__ int stmp[256];
    const int b = blockIdx.x;
    const int t = threadIdx.x;
    const int wv = t >> 6;
    // ebeg = sum counts[0..b)  (nb = 391 > 256: strided pre-sum, then tree)
    int s0 = 0;
    for (int j = t; j < b; j += 256) s0 += counts[j];
    stmp[t] = s0;
    __syncthreads();
    for (int off = 128; off; off >>= 1) {
        if (t < off) stmp[t] += stmp[t + off];
        __syncthreads();
    }
    const int ebeg = stmp[0];
    const int ecnt = counts[b];
    __syncthreads();
    const unsigned* bp = binned + (size_t)b * BCAP;
    for (int i = t; i < 4 * BSZ; i += 256) (&c[0][0])[i] = 0;
    __syncthreads();
    for (int e = t; e < ecnt; e += 256)
        atomicAdd(&c[wv][bp[e] >> 17], 1);
    __syncthreads();
    int c0 = c[0][t], c1 = c[1][t], c2 = c[2][t], c3 = c[3][t];
    int s = c0 + c1 + c2 + c3;           // deg of node t in this bucket
    stmp[t] = s;
    __syncthreads();
    for (int off = 1; off < 256; off <<= 1) {
        int u = (t >= off) ? stmp[t - off] : 0;
        __syncthreads();
        stmp[t] += u;
        __syncthreads();
    }
    const int ex = stmp[t] - s;          // exclusive prefix within bucket
    const int g = (b << SHIFT) + t;
    if (g < n) {
        rowptr[g] = (int)(((unsigned)(ebeg + ex) << 8) | (unsigned)min(s, 255));
        dinv[g] = rsqrtf((float)s + 1.0f);
    }
    c[0][t] = ex;
    c[1][t] = ex + c0;
    c[2][t] = ex + c0 + c1;
    c[3][t] = ex + c0 + c1 + c2;
    __syncthreads();
    for (int e = t; e < ecnt; e += 256) {
        unsigned p = bp[e];
        int j = p >> 17;
        int off = atomicAdd(&c[wv][j], 1);
        colidx[ebeg + off] = (int)((p & 0x1FFFFu) << 7);  // byte offset of src row
    }
}

// MFMA GEMM: C16[n,64] = fp16( (A[n,K] @ W[K,64]) * dinv[row] ).
// Block = 256 threads = 4 waves; wave w computes rows rb+w*16..+15, all 64 cols.
template <int K, bool A_FP32>
__global__ __launch_bounds__(256) void k_gemm_mfma(const void* __restrict__ Av,
                                                   const float* __restrict__ W,
                                                   const float* __restrict__ dinv,
                                                   __half* __restrict__ C, int n) {
    constexpr int KP = K + 8;  // padded LDS row stride in halves (16B aligned)
    __shared__ _Float16 Wt[64 * KP];
    const int tid = threadIdx.x;
    for (int i = tid; i < K * 64; i += 256) {
        int k = i >> 6, c = i & 63;
        Wt[c * KP + k] = (_Float16)W[i];
    }
    __syncthreads();

    const int lane = tid & 63;
    const int wv = tid >> 6;
    const int r16 = lane & 15;
    const int kq = lane >> 4;                       // 0..3
    const int rb = blockIdx.x * 64 + wv * 16;
    const int arow = min(rb + r16, n - 1);          // clamped A row for this lane

    f32x4 acc[4] = {{0.f,0.f,0.f,0.f},{0.f,0.f,0.f,0.f},
                    {0.f,0.f,0.f,0.f},{0.f,0.f,0.f,0.f}};

#pragma unroll
    for (int kk = 0; kk < K; kk += 32) {
        f16x8 a;
        if (A_FP32) {
            const float* Ap = (const float*)Av + (size_t)arow * K + kk + kq * 8;
            float4 f0 = *reinterpret_cast<const float4*>(Ap);
            float4 f1 = *reinterpret_cast<const float4*>(Ap + 4);
            a[0] = (_Float16)f0.x; a[1] = (_Float16)f0.y;
            a[2] = (_Float16)f0.z; a[3] = (_Float16)f0.w;
            a[4] = (_Float16)f1.x; a[5] = (_Float16)f1.y;
            a[6] = (_Float16)f1.z; a[7] = (_Float16)f1.w;
        } else {
            const _Float16* Ap = (const _Float16*)Av + (size_t)arow * K + kk + kq * 8;
            a = *reinterpret_cast<const f16x8*>(Ap);
        }
#pragma unroll
        for (int nt = 0; nt < 4; ++nt) {
            f16x8 b = *reinterpret_cast<const f16x8*>(&Wt[(nt * 16 + r16) * KP + kk + kq * 8]);
            acc[nt] = __builtin_amdgcn_mfma_f32_16x16x32_f16(a, b, acc[nt], 0, 0, 0);
        }
    }

#pragma unroll
    for (int r = 0; r < 4; ++r) {
        const int row = rb + kq * 4 + r;
        if (row < n) {
            const float di = dinv[row];
#pragma unroll
            for (int nt = 0; nt < 4; ++nt)
                C[((size_t)row << 6) + nt * 16 + r16] = __float2half(acc[nt][r] * di);
        }
    }
}

// Accumulate 8 fp16 (one uint4) into acc[8] via v_dot2_f32_f16: one VALU op per
// value (convert+add fused, fp32 accumulate). Masks (1,0)/(0,1) keep channels
// separate; exact 1.0-multiply => bit-identical to cvt+add.
__device__ __forceinline__ void dotu4(float acc[8], uint4 u, f16x2 pl, f16x2 ph) {
    union { uint4 u4; f16x2 h[4]; } v;
    v.u4 = u;
    acc[0] = __builtin_amdgcn_fdot2(v.h[0], pl, acc[0], false);
    acc[1] = __builtin_amdgcn_fdot2(v.h[0], ph, acc[1], false);
    acc[2] = __builtin_amdgcn_fdot2(v.h[1], pl, acc[2], false);
    acc[3] = __builtin_amdgcn_fdot2(v.h[1], ph, acc[3], false);
    acc[4] = __builtin_amdgcn_fdot2(v.h[2], pl, acc[4], false);
    acc[5] = __builtin_amdgcn_fdot2(v.h[2], ph, acc[5], false);
    acc[6] = __builtin_amdgcn_fdot2(v.h[3], pl, acc[6], false);
    acc[7] = __builtin_amdgcn_fdot2(v.h[3], ph, acc[7], false);
}

// Fold partial sums across the 8 groups: after this every lane holds the full
// sums for its channel-slice p.
__device__ __forceinline__ void fold8(float acc[8]) {
#pragma unroll
    for (int m = 8; m <= 32; m <<= 1) {
#pragma unroll
        for (int j = 0; j < 8; ++j)
            acc[j] += __shfl_xor(acc[j], m, 64);
    }
}

// 2-node pipelined gather (R14, unchanged). Wave = 8 groups x 8 lanes; each
// group's uint4 load fetches one full 128B row. ALL loads for both nodes
// issued back-to-back (8 colidx dwords, then 8 gather uint4s = 16 VMEM in
// flight); node0's dot2s overlap node1's in-flight gathers. Unconditional 4
// slots per node (deg<=32, ~all nodes; dummy-masked loads broadcast the hot
// zero row). Tail loops only for deg>32 (~1%), after the main dots.
__device__ __forceinline__ void gather_pair(const char* __restrict__ hsb,
                                            const int* __restrict__ colidx,
                                            unsigned pk0, unsigned pk1,
                                            int g, int p, unsigned dum,
                                            float acc0[8], float acc1[8]) {
    const f16x2 pl = {(_Float16)1.0f, (_Float16)0.0f};
    const f16x2 ph = {(_Float16)0.0f, (_Float16)1.0f};
    const int beg0 = (int)(pk0 >> 8), deg0 = (int)(pk0 & 255u);
    const int beg1 = (int)(pk1 >> 8), deg1 = (int)(pk1 & 255u);
    const int t0 = deg0 - g, t1 = deg1 - g;   // slot k valid iff 8*k < t
    const unsigned poff = (unsigned)(p << 4);
    const unsigned dumo = dum + poff;
    const int ia = beg0 + g;
    const int ib = beg1 + g;
    // --- issue all 8 colidx loads (slack past E is safe) ---
    unsigned a0 = (unsigned)colidx[ia]      + poff;
    unsigned a1 = (unsigned)colidx[ia + 8]  + poff;
    unsigned a2 = (unsigned)colidx[ia + 16] + poff;
    unsigned a3 = (unsigned)colidx[ia + 24] + poff;
    unsigned b0 = (unsigned)colidx[ib]      + poff;
    unsigned b1 = (unsigned)colidx[ib + 8]  + poff;
    unsigned b2 = (unsigned)colidx[ib + 16] + poff;
    unsigned b3 = (unsigned)colidx[ib + 24] + poff;
    unsigned oa0 = (0  < t0) ? a0 : dumo;
    unsigned oa1 = (8  < t0) ? a1 : dumo;
    unsigned oa2 = (16 < t0) ? a2 : dumo;
    unsigned oa3 = (24 < t0) ? a3 : dumo;
    unsigned ob0 = (0  < t1) ? b0 : dumo;
    unsigned ob1 = (8  < t1) ? b1 : dumo;
    unsigned ob2 = (16 < t1) ? b2 : dumo;
    unsigned ob3 = (24 < t1) ? b3 : dumo;
    // --- issue all 8 gathers ---
    uint4 ua0 = *reinterpret_cast<const uint4*>(hsb + oa0);
    uint4 ua1 = *reinterpret_cast<const uint4*>(hsb + oa1);
    uint4 ua2 = *reinterpret_cast<const uint4*>(hsb + oa2);
    uint4 ua3 = *reinterpret_cast<const uint4*>(hsb + oa3);
    uint4 ub0 = *reinterpret_cast<const uint4*>(hsb + ob0);
    uint4 ub1 = *reinterpret_cast<const uint4*>(hsb + ob1);
    uint4 ub2 = *reinterpret_cast<const uint4*>(hsb + ob2);
    uint4 ub3 = *reinterpret_cast<const uint4*>(hsb + ob3);
    // --- consume node0 while node1's gathers are still in flight ---
    dotu4(acc0, ua0, pl, ph);
    dotu4(acc0, ua1, pl, ph);
    dotu4(acc0, ua2, pl, ph);
    dotu4(acc0, ua3, pl, ph);
    dotu4(acc1, ub0, pl, ph);
    dotu4(acc1, ub1, pl, ph);
    dotu4(acc1, ub2, pl, ph);
    dotu4(acc1, ub3, pl, ph);
    // --- rare tails (deg > 32), wave-uniform, after the main dots ---
    const int ns0 = (deg0 + 7) >> 3;
    for (int k = 4; k < ns0; k += 4) {
        const int ik = beg0 + 8 * k + g;
        unsigned c0 = (unsigned)colidx[ik]      + poff;
        unsigned c1 = (unsigned)colidx[ik + 8]  + poff;
        unsigned c2 = (unsigned)colidx[ik + 16] + poff;
        unsigned c3 = (unsigned)colidx[ik + 24] + poff;
        const int kb = 8 * k;
        uint4 u0 = *reinterpret_cast<const uint4*>(hsb + ((kb      < t0) ? c0 : dumo));
        uint4 u1 = *reinterpret_cast<const uint4*>(hsb + ((kb + 8  < t0) ? c1 : dumo));
        uint4 u2 = *reinterpret_cast<const uint4*>(hsb + ((kb + 16 < t0) ? c2 : dumo));
        uint4 u3 = *reinterpret_cast<const uint4*>(hsb + ((kb + 24 < t0) ? c3 : dumo));
        dotu4(acc0, u0, pl, ph);
        dotu4(acc0, u1, pl, ph);
        dotu4(acc0, u2, pl, ph);
        dotu4(acc0, u3, pl, ph);
    }
    const int ns1 = (deg1 + 7) >> 3;
    for (int k = 4; k < ns1; k += 4) {
        const int ik = beg1 + 8 * k + g;
        unsigned c0 = (unsigned)colidx[ik]      + poff;
        unsigned c1 = (unsigned)colidx[ik + 8]  + poff;
        unsigned c2 = (unsigned)colidx[ik + 16] + poff;
        unsigned c3 = (unsigned)colidx[ik + 24] + poff;
        const int kb = 8 * k;
        uint4 u0 = *reinterpret_cast<const uint4*>(hsb + ((kb      < t1) ? c0 : dumo));
        uint4 u1 = *reinterpret_cast<const uint4*>(hsb + ((kb + 8  < t1) ? c1 : dumo));
        uint4 u2 = *reinterpret_cast<const uint4*>(hsb + ((kb + 16 < t1) ? c2 : dumo));
        uint4 u3 = *reinterpret_cast<const uint4*>(hsb + ((kb + 24 < t1) ? c3 : dumo));
        dotu4(acc1, u0, pl, ph);
        dotu4(acc1, u1, pl, ph);
        dotu4(acc1, u2, pl, ph);
        dotu4(acc1, u3, pl, ph);
    }
    fold8(acc0);
    fold8(acc1);
}

// conv1 aggregation: out16 = fp16(relu(di*(sum_e hs[src_e] + hs_i) + b)).
// 2 nodes per wave; epilogue once: lanes 0-7 -> node0, lanes 8-15 -> node1.
__global__ __launch_bounds__(256) void k_agg_relu(const __half* __restrict__ hs,
                                                  const int* __restrict__ rowptr,
                                                  const int* __restrict__ colidx,
                                                  const float* __restrict__ dinv,
                                                  const float* __restrict__ b,
                                                  __half* __restrict__ out, int n) {
    const int wv = threadIdx.x >> 6;
    const int i0 = blockIdx.x * 8 + wv * 2;
    const int lane = threadIdx.x & 63;
    if (i0 >= n) return;
    const int i1 = min(i0 + 1, n - 1);
    const int g = lane >> 3, p = lane & 7;
    const int iw = (lane & 8) ? i1 : i0;
    const unsigned pk0 = (unsigned)rowptr[i0];
    const unsigned pk1 = (unsigned)rowptr[i1];
    uint4 su = *reinterpret_cast<const uint4*>(hs + ((size_t)iw << 6) + (p << 3));
    const float di = dinv[iw];
    float acc0[8] = {}, acc1[8] = {};
    gather_pair((const char*)hs, colidx, pk0, pk1, g, p, (unsigned)n << 7,
                acc0, acc1);
    if (lane < 16) {
        const f16x2 pl = {(_Float16)1.0f, (_Float16)0.0f};
        const f16x2 ph = {(_Float16)0.0f, (_Float16)1.0f};
        float a[8];
#pragma unroll
        for (int j = 0; j < 8; ++j) a[j] = (lane & 8) ? acc1[j] : acc0[j];
        dotu4(a, su, pl, ph);
        float4 b0 = *reinterpret_cast<const float4*>(b + (p << 3));
        float4 b1 = *reinterpret_cast<const float4*>(b + (p << 3) + 4);
        __half2 h0 = __halves2half2(__float2half(fmaxf(fmaf(a[0], di, b0.x), 0.f)),
                                    __float2half(fmaxf(fmaf(a[1], di, b0.y), 0.f)));
        __half2 h1 = __halves2half2(__float2half(fmaxf(fmaf(a[2], di, b0.z), 0.f)),
                                    __float2half(fmaxf(fmaf(a[3], di, b0.w), 0.f)));
        __half2 h2 = __halves2half2(__float2half(fmaxf(fmaf(a[4], di, b1.x), 0.f)),
                                    __float2half(fmaxf(fmaf(a[5], di, b1.y), 0.f)));
        __half2 h3 = __halves2half2(__float2half(fmaxf(fmaf(a[6], di, b1.z), 0.f)),
                                    __float2half(fmaxf(fmaf(a[7], di, b1.w), 0.f)));
        uint4 u;
        u.x = *reinterpret_cast<unsigned*>(&h0);
        u.y = *reinterpret_cast<unsigned*>(&h1);
        u.z = *reinterpret_cast<unsigned*>(&h2);
        u.w = *reinterpret_cast<unsigned*>(&h3);
        if (iw < n && (i0 + 1 < n || !(lane & 8)))
            *reinterpret_cast<uint4*>(out + ((size_t)iw << 6) + (p << 3)) = u;
    }
}

// conv2 aggregation + relu + (.@Wl + bl) head, fused. 2 nodes per wave;
// xor-1,2,4 reduce stays within each 8-lane group -> lane0 holds v(node0),
// lane8 holds v(node1).
__global__ __launch_bounds__(256) void k_agg_head(const __half* __restrict__ hs,
                                                  const int* __restrict__ rowptr,
                                                  const int* __restrict__ colidx,
                                                  const float* __restrict__ dinv,
                                                  const float* __restrict__ b2,
                                                  const float* __restrict__ Wl,
                                                  const float* __restrict__ bl,
                                                  float* __restrict__ out, int n) {
    const int wv = threadIdx.x >> 6;
    const int i0 = blockIdx.x * 8 + wv * 2;
    const int lane = threadIdx.x & 63;
    if (i0 >= n) return;
    const int i1 = min(i0 + 1, n - 1);
    const int g = lane >> 3, p = lane & 7;
    const int iw = (lane & 8) ? i1 : i0;
    const unsigned pk0 = (unsigned)rowptr[i0];
    const unsigned pk1 = (unsigned)rowptr[i1];
    uint4 su = *reinterpret_cast<const uint4*>(hs + ((size_t)iw << 6) + (p << 3));
    const float di = dinv[iw];
    float acc0[8] = {}, acc1[8] = {};
    gather_pair((const char*)hs, colidx, pk0, pk1, g, p, (unsigned)n << 7,
                acc0, acc1);
    const f16x2 pl = {(_Float16)1.0f, (_Float16)0.0f};
    const f16x2 ph = {(_Float16)0.0f, (_Float16)1.0f};
    float a[8];
#pragma unroll
    for (int j = 0; j < 8; ++j) a[j] = (lane & 8) ? acc1[j] : acc0[j];
    dotu4(a, su, pl, ph);
    float4 b0 = *reinterpret_cast<const float4*>(b2 + (p << 3));
    float4 b1 = *reinterpret_cast<const float4*>(b2 + (p << 3) + 4);
    float4 w0 = *reinterpret_cast<const float4*>(Wl + (p << 3));
    float4 w1 = *reinterpret_cast<const float4*>(Wl + (p << 3) + 4);
    float v = fmaxf(fmaf(a[0], di, b0.x), 0.f) * w0.x
            + fmaxf(fmaf(a[1], di, b0.y), 0.f) * w0.y
            + fmaxf(fmaf(a[2], di, b0.z), 0.f) * w0.z
            + fmaxf(fmaf(a[3], di, b0.w), 0.f) * w0.w
            + fmaxf(fmaf(a[4], di, b1.x), 0.f) * w1.x
            + fmaxf(fmaf(a[5], di, b1.y), 0.f) * w1.y
            + fmaxf(fmaf(a[6], di, b1.z), 0.f) * w1.z
            + fmaxf(fmaf(a[7], di, b1.w), 0.f) * w1.w;
    v += __shfl_xor(v, 1, 64);
    v += __shfl_xor(v, 2, 64);
    v += __shfl_xor(v, 4, 64);
    if (lane == 0) out[i0] = v + bl[0];
    if (lane == 8 && i0 + 1 < n) out[i1] = v + bl[0];
}

extern "C" void kernel_launch(void* const* d_in, const int* in_sizes, int n_in,
                              void* d_out, int out_size, void* d_ws, size_t ws_size,
                              hipStream_t stream) {
    const float* x  = (const float*)d_in[0];
    const int*   ei = (const int*)d_in[1];
    const float* W1 = (const float*)d_in[2];
    const float* b1 = (const float*)d_in[3];
    const float* W2 = (const float*)d_in[4];
    const float* b2 = (const float*)d_in[5];
    const float* Wl = (const float*)d_in[6];
    const float* bl = (const float*)d_in[7];
    float* out = (float*)d_out;

    const int n = in_sizes[0] / 128;   // 100000
    const int E = in_sizes[1] / 2;     // 1600000
    const int* src = ei;
    const int* dst = ei + E;
    const int nb = (n + BSZ - 1) >> SHIFT;  // 391

    char* ws = (char*)d_ws;
    size_t o = 0;
    auto alloc = [&](size_t bytes) {
        void* p = ws + o;
        o = (o + bytes + 255) & ~(size_t)255;
        return p;
    };
    float* dinv    = (float*)alloc((size_t)n * 4);
    int*   bcursor = (int*)  alloc((size_t)NBMAX * 4);
    int*   rowptr  = (int*)  alloc((size_t)(n + 1) * 4);
    int*   colidx  = (int*)  alloc(((size_t)E + 64) * 4);        // +slack for unrolled reads
    __half* hs     = (__half*)alloc((size_t)(n + 1) * 64 * 2);   // +1 zeroed dummy row
    __half* bufA   = (__half*)alloc((size_t)n * 64 * 2);         // fp16 relu output
    unsigned* binned = (unsigned*)alloc((size_t)nb * BCAP * 4);  // bucketed edges

    // ---- CSR build (wave-private counting sort) ----
    hipMemsetAsync(bcursor, 0, NBMAX * sizeof(int), stream);
    k_bin<<<(E + BIN_CH - 1) / BIN_CH, 256, 0, stream>>>(src, dst, bcursor, binned,
                                                         hs, n, E);
    k_bfill<<<nb, 256, 0, stream>>>(binned, bcursor, rowptr, colidx, dinv, n);

    // ---- conv1 ----
    k_gemm_mfma<128, true><<<(n + 63) / 64, 256, 0, stream>>>(x, W1, dinv, hs, n);
    k_agg_relu<<<(n + 7) / 8, 256, 0, stream>>>(hs, rowptr, colidx, dinv, b1, bufA, n);

    // ---- conv2 + head ----
    k_gemm_mfma<64, false><<<(n + 63) / 64, 256, 0, stream>>>(bufA, W2, dinv, hs, n);
    k_agg_head<<<(n + 7) / 8, 256, 0, stream>>>(hs, rowptr, colidx, dinv, b2, Wl, bl,
                                                out, n);
}

// Round 7
// 153.836 us; speedup vs baseline: 1.5197x; 1.0830x over previous
//
#include <hip/hip_runtime.h>
#include <hip/hip_fp16.h>

// GCNRegressor: x[n,128] --GCNConv(W1)--> relu --GCNConv(W2)--> relu --@Wl+bl--> out[n]
// n=100000, E=1600000, IN=128, HID=64.
// R1-R10: CSR+gather, counting sort, fp16 features, MFMA GEMMs: 2913 -> 171 us.
// R11: 8-rows-per-VMEM gather (wave = 8 groups x 8 lanes, uint4/lane): 41.8us agg.
// R12/R13: dot2 + fewer slots: VALU -25% but dur +3..15%. LESSON: agg is
//      LATENCY-bound; issue all loads back-to-back, no branches in between.
// R14: 2 nodes per wave, software-pipelined (16 VMEM in flight): 162 -> 148.7. BEST.
// R15: fixed-slot cfix: k_bin exposed at 40us. R16: global scatter: 15x write
//      amp, 233us. R17: smaller chunks/buckets: runs shrank to 2.6 edges ->
//      6x write amp on binned, k_bin 57-66us. RULE: every 64B line of a store
//      stream must be filled by ONE block.
// R18: block-major binned. Each block counting-sorts its 1024-edge chunk into
//      a PRIVATE contiguous 4KB region (LDS hist+scan, no global cursors, no
//      memset) + writes its 197-int bucket-offset row gbase[blk] (coalesced).
//      ebeg(b) = sum_blk gbase[blk][b]. k_bfill (1 block/bucket) rebuilds the
//      bucket edge list via an LDS posmap of binned indices (segment starts
//      from gbase; intra-bucket order irrelevant), then the proven two-pass
//      count/scan/place over stride-256 independent loads. All store streams
//      line-private. Aggs/GEMMs = R14 verbatim.

#define SHIFT 9
#define BSZ   (1 << SHIFT)     // 512 nodes per bucket
#define NBMAX 256              // >= nb = 196
#define BIN_CH 1024            // edges per k_bin block (private region)
#define PMAX  12288            // bucket edge capacity (mean 8192, +45 sigma)

using f16x8 = __attribute__((ext_vector_type(8))) _Float16;
using f16x2 = __attribute__((ext_vector_type(2))) _Float16;
using f32x4 = __attribute__((ext_vector_type(4))) float;

// ---- Phase 1: per-block counting sort into private binned region ----
// binned[blk*BIN_CH + ex[bucket] ...] sorted by bucket; gbase[blk*(nb+1)+i] =
// exclusive prefix of this block's bucket counts (row i=nb = chunk total).
// pack: src(17b) | local_node(9b)<<17. Block 0 also zeroes the dummy hs row.
__global__ __launch_bounds__(256) void k_bin(const int* __restrict__ src,
                                             const int* __restrict__ dst,
                                             unsigned* __restrict__ binned,
                                             int* __restrict__ gbase,
                                             __half* __restrict__ hs,
                                             int n, int nb, int E) {
    if (blockIdx.x == 0 && threadIdx.x < 8) {
        uint4 z = {0u, 0u, 0u, 0u};
        reinterpret_cast<uint4*>(hs + ((size_t)n << 6))[threadIdx.x] = z;
    }
    __shared__ int h[NBMAX];
    __shared__ int ex[NBMAX + 1];
    __shared__ int cur[NBMAX];
    __shared__ int stmp[256];
    const int t = threadIdx.x;
    const int blk = blockIdx.x;
    const int beg = blk * BIN_CH;
    for (int i = t; i < NBMAX; i += 256) h[i] = 0;
    __syncthreads();
    const int e4 = beg + t * 4;
    const bool act = e4 < E;               // E % 4 == 0: all-or-nothing per thread
    int4 d4 = {0, 0, 0, 0};
    if (act) {
        d4 = *reinterpret_cast<const int4*>(dst + e4);
        atomicAdd(&h[d4.x >> SHIFT], 1);
        atomicAdd(&h[d4.y >> SHIFT], 1);
        atomicAdd(&h[d4.z >> SHIFT], 1);
        atomicAdd(&h[d4.w >> SHIFT], 1);
    }
    __syncthreads();
    const int hv = (t < nb) ? h[t] : 0;
    stmp[t] = hv;
    __syncthreads();
    for (int off = 1; off < 256; off <<= 1) {
        int u = (t >= off) ? stmp[t - off] : 0;
        __syncthreads();
        stmp[t] += u;
        __syncthreads();
    }
    if (t <= nb) ex[t] = stmp[t] - ((t < nb) ? h[t] : 0);  // t==nb -> chunk total
    __syncthreads();
    if (t < nb) cur[t] = ex[t];
    if (t <= nb) gbase[(size_t)blk * (nb + 1) + t] = ex[t];  // coalesced, private
    __syncthreads();
    if (act) {
        const int4 s4 = *reinterpret_cast<const int4*>(src + e4);
        int b0 = d4.x >> SHIFT, b1 = d4.y >> SHIFT;
        int b2 = d4.z >> SHIFT, b3 = d4.w >> SHIFT;
        int p0 = atomicAdd(&cur[b0], 1);
        int p1 = atomicAdd(&cur[b1], 1);
        int p2 = atomicAdd(&cur[b2], 1);
        int p3 = atomicAdd(&cur[b3], 1);
        binned[beg + p0] = (unsigned)s4.x | ((unsigned)(d4.x & (BSZ - 1)) << 17);
        binned[beg + p1] = (unsigned)s4.y | ((unsigned)(d4.y & (BSZ - 1)) << 17);
        binned[beg + p2] = (unsigned)s4.z | ((unsigned)(d4.z & (BSZ - 1)) << 17);
        binned[beg + p3] = (unsigned)s4.w | ((unsigned)(d4.w & (BSZ - 1)) << 17);
    }
}

// ---- Phase 2: one block per bucket. Rebuild edge list via posmap (binned
// indices of this bucket's segments across all k_bin blocks), then count per
// node, scan, write packed rowptr + dinv, place colidx. ----
// rowptr[g] = (edge_base << 8) | min(deg,255) ; colidx entry = src_byte_off.
__global__ __launch_bounds__(256) void k_bfill(const unsigned* __restrict__ binned,
                                               const int* __restrict__ gbase,
                                               int nblk, int nb,
                                               int* __restrict__ rowptr,
                                               int* __restrict__ colidx,
                                               float* __restrict__ dinv, int n) {
    __shared__ int posmap[PMAX];   // 48 KB
    __shared__ int cnt[BSZ];
    __shared__ int nbase[BSZ];
    __shared__ int stmp[256];
    __shared__ int sh_tot;
    const int b = blockIdx.x;
    const int t = threadIdx.x;
    if (t == 0) sh_tot = 0;
    for (int i = t; i < BSZ; i += 256) cnt[i] = 0;
    __syncthreads();
    // posmap build + ebeg partial: segment of bucket b in block blk spans
    // [gbase[blk][b], gbase[blk][b+1]) within binned[blk*BIN_CH ...].
    int ebeg_part = 0;
    for (int blk = t; blk < nblk; blk += 256) {
        const int* gb = gbase + (size_t)blk * (nb + 1) + b;
        const int s0 = gb[0];
        const int s1 = gb[1];
        ebeg_part += s0;
        const int c = s1 - s0;
        if (c > 0) {
            int pos = atomicAdd(&sh_tot, c);
            const int base = blk * BIN_CH + s0;
            for (int k = 0; k < c; ++k)
                if (pos + k < PMAX) posmap[pos + k] = base + k;
        }
    }
    stmp[t] = ebeg_part;
    __syncthreads();
    for (int off = 128; off; off >>= 1) {
        if (t < off) stmp[t] += stmp[t + off];
        __syncthreads();
    }
    const int ebeg = stmp[0];
    const int ecnt = min(sh_tot, PMAX);
    __syncthreads();
    // pass A: per-node counts
    for (int j = t; j < ecnt; j += 256)
        atomicAdd(&cnt[binned[posmap[j]] >> 17], 1);
    __syncthreads();
    // node scan (512 nodes, 2 per thread)
    int c0 = cnt[2 * t], c1 = cnt[2 * t + 1];
    int s = c0 + c1;
    stmp[t] = s;
    __syncthreads();
    for (int off = 1; off < 256; off <<= 1) {
        int u = (t >= off) ? stmp[t - off] : 0;
        __syncthreads();
        stmp[t] += u;
        __syncthreads();
    }
    const int ex = stmp[t] - s;
    nbase[2 * t] = ex;
    nbase[2 * t + 1] = ex + c0;
    __syncthreads();
    const int gb9 = b << SHIFT;
    for (int j = t; j < BSZ; j += 256) {
        const int g = gb9 + j;
        if (g < n) {
            rowptr[g] = (int)(((unsigned)(ebeg + nbase[j]) << 8) |
                              (unsigned)min(cnt[j], 255));
            dinv[g] = rsqrtf((float)cnt[j] + 1.0f);
        }
        cnt[j] = nbase[j];   // becomes local cursor
    }
    __syncthreads();
    // pass B: place (colidx region is bucket-private)
    for (int j = t; j < ecnt; j += 256) {
        const unsigned e = binned[posmap[j]];
        const int lo = (int)(e >> 17);
        const int off = atomicAdd(&cnt[lo], 1);
        colidx[ebeg + off] = (int)((e & 0x1FFFFu) << 7);  // byte offset of src row
    }
}

// MFMA GEMM: C16[n,64] = fp16( (A[n,K] @ W[K,64]) * dinv[row] ).
// Block = 256 threads = 4 waves; wave w computes rows rb+w*16..+15, all 64 cols.
template <int K, bool A_FP32>
__global__ __launch_bounds__(256) void k_gemm_mfma(const void* __restrict__ Av,
                                                   const float* __restrict__ W,
                                                   const float* __restrict__ dinv,
                                                   __half* __restrict__ C, int n) {
    constexpr int KP = K + 8;  // padded LDS row stride in halves (16B aligned)
    __shared__ _Float16 Wt[64 * KP];
    const int tid = threadIdx.x;
    for (int i = tid; i < K * 64; i += 256) {
        int k = i >> 6, c = i & 63;
        Wt[c * KP + k] = (_Float16)W[i];
    }
    __syncthreads();

    const int lane = tid & 63;
    const int wv = tid >> 6;
    const int r16 = lane & 15;
    const int kq = lane >> 4;                       // 0..3
    const int rb = blockIdx.x * 64 + wv * 16;
    const int arow = min(rb + r16, n - 1);          // clamped A row for this lane

    f32x4 acc[4] = {{0.f,0.f,0.f,0.f},{0.f,0.f,0.f,0.f},
                    {0.f,0.f,0.f,0.f},{0.f,0.f,0.f,0.f}};

#pragma unroll
    for (int kk = 0; kk < K; kk += 32) {
        f16x8 a;
        if (A_FP32) {
            const float* Ap = (const float*)Av + (size_t)arow * K + kk + kq * 8;
            float4 f0 = *reinterpret_cast<const float4*>(Ap);
            float4 f1 = *reinterpret_cast<const float4*>(Ap + 4);
            a[0] = (_Float16)f0.x; a[1] = (_Float16)f0.y;
            a[2] = (_Float16)f0.z; a[3] = (_Float16)f0.w;
            a[4] = (_Float16)f1.x; a[5] = (_Float16)f1.y;
            a[6] = (_Float16)f1.z; a[7] = (_Float16)f1.w;
        } else {
            const _Float16* Ap = (const _Float16*)Av + (size_t)arow * K + kk + kq * 8;
            a = *reinterpret_cast<const f16x8*>(Ap);
        }
#pragma unroll
        for (int nt = 0; nt < 4; ++nt) {
            f16x8 b = *reinterpret_cast<const f16x8*>(&Wt[(nt * 16 + r16) * KP + kk + kq * 8]);
            acc[nt] = __builtin_amdgcn_mfma_f32_16x16x32_f16(a, b, acc[nt], 0, 0, 0);
        }
    }

#pragma unroll
    for (int r = 0; r < 4; ++r) {
        const int row = rb + kq * 4 + r;
        if (row < n) {
            const float di = dinv[row];
#pragma unroll
            for (int nt = 0; nt < 4; ++nt)
                C[((size_t)row << 6) + nt * 16 + r16] = __float2half(acc[nt][r] * di);
        }
    }
}

// Accumulate 8 fp16 (one uint4) into acc[8] via v_dot2_f32_f16: one VALU op per
// value (convert+add fused, fp32 accumulate). Masks (1,0)/(0,1) keep channels
// separate; exact 1.0-multiply => bit-identical to cvt+add.
__device__ __forceinline__ void dotu4(float acc[8], uint4 u, f16x2 pl, f16x2 ph) {
    union { uint4 u4; f16x2 h[4]; } v;
    v.u4 = u;
    acc[0] = __builtin_amdgcn_fdot2(v.h[0], pl, acc[0], false);
    acc[1] = __builtin_amdgcn_fdot2(v.h[0], ph, acc[1], false);
    acc[2] = __builtin_amdgcn_fdot2(v.h[1], pl, acc[2], false);
    acc[3] = __builtin_amdgcn_fdot2(v.h[1], ph, acc[3], false);
    acc[4] = __builtin_amdgcn_fdot2(v.h[2], pl, acc[4], false);
    acc[5] = __builtin_amdgcn_fdot2(v.h[2], ph, acc[5], false);
    acc[6] = __builtin_amdgcn_fdot2(v.h[3], pl, acc[6], false);
    acc[7] = __builtin_amdgcn_fdot2(v.h[3], ph, acc[7], false);
}

// Fold partial sums across the 8 groups: after this every lane holds the full
// sums for its channel-slice p.
__device__ __forceinline__ void fold8(float acc[8]) {
#pragma unroll
    for (int m = 8; m <= 32; m <<= 1) {
#pragma unroll
        for (int j = 0; j < 8; ++j)
            acc[j] += __shfl_xor(acc[j], m, 64);
    }
}

// 2-node pipelined gather (R14, unchanged). Wave = 8 groups x 8 lanes; each
// group's uint4 load fetches one full 128B row. ALL loads for both nodes
// issued back-to-back (8 colidx dwords, then 8 gather uint4s = 16 VMEM in
// flight); node0's dot2s overlap node1's in-flight gathers. Unconditional 4
// slots per node (deg<=32, ~all nodes; dummy-masked loads broadcast the hot
// zero row). Tail loops only for deg>32 (~1%), after the main dots.
__device__ __forceinline__ void gather_pair(const char* __restrict__ hsb,
                                            const int* __restrict__ colidx,
                                            unsigned pk0, unsigned pk1,
                                            int g, int p, unsigned dum,
                                            float acc0[8], float acc1[8]) {
    const f16x2 pl = {(_Float16)1.0f, (_Float16)0.0f};
    const f16x2 ph = {(_Float16)0.0f, (_Float16)1.0f};
    const int beg0 = (int)(pk0 >> 8), deg0 = (int)(pk0 & 255u);
    const int beg1 = (int)(pk1 >> 8), deg1 = (int)(pk1 & 255u);
    const int t0 = deg0 - g, t1 = deg1 - g;   // slot k valid iff 8*k < t
    const unsigned poff = (unsigned)(p << 4);
    const unsigned dumo = dum + poff;
    const int ia = beg0 + g;
    const int ib = beg1 + g;
    // --- issue all 8 colidx loads (slack past E is safe) ---
    unsigned a0 = (unsigned)colidx[ia]      + poff;
    unsigned a1 = (unsigned)colidx[ia + 8]  + poff;
    unsigned a2 = (unsigned)colidx[ia + 16] + poff;
    unsigned a3 = (unsigned)colidx[ia + 24] + poff;
    unsigned b0 = (unsigned)colidx[ib]      + poff;
    unsigned b1 = (unsigned)colidx[ib + 8]  + poff;
    unsigned b2 = (unsigned)colidx[ib + 16] + poff;
    unsigned b3 = (unsigned)colidx[ib + 24] + poff;
    unsigned oa0 = (0  < t0) ? a0 : dumo;
    unsigned oa1 = (8  < t0) ? a1 : dumo;
    unsigned oa2 = (16 < t0) ? a2 : dumo;
    unsigned oa3 = (24 < t0) ? a3 : dumo;
    unsigned ob0 = (0  < t1) ? b0 : dumo;
    unsigned ob1 = (8  < t1) ? b1 : dumo;
    unsigned ob2 = (16 < t1) ? b2 : dumo;
    unsigned ob3 = (24 < t1) ? b3 : dumo;
    // --- issue all 8 gathers ---
    uint4 ua0 = *reinterpret_cast<const uint4*>(hsb + oa0);
    uint4 ua1 = *reinterpret_cast<const uint4*>(hsb + oa1);
    uint4 ua2 = *reinterpret_cast<const uint4*>(hsb + oa2);
    uint4 ua3 = *reinterpret_cast<const uint4*>(hsb + oa3);
    uint4 ub0 = *reinterpret_cast<const uint4*>(hsb + ob0);
    uint4 ub1 = *reinterpret_cast<const uint4*>(hsb + ob1);
    uint4 ub2 = *reinterpret_cast<const uint4*>(hsb + ob2);
    uint4 ub3 = *reinterpret_cast<const uint4*>(hsb + ob3);
    // --- consume node0 while node1's gathers are still in flight ---
    dotu4(acc0, ua0, pl, ph);
    dotu4(acc0, ua1, pl, ph);
    dotu4(acc0, ua2, pl, ph);
    dotu4(acc0, ua3, pl, ph);
    dotu4(acc1, ub0, pl, ph);
    dotu4(acc1, ub1, pl, ph);
    dotu4(acc1, ub2, pl, ph);
    dotu4(acc1, ub3, pl, ph);
    // --- rare tails (deg > 32), wave-uniform, after the main dots ---
    const int ns0 = (deg0 + 7) >> 3;
    for (int k = 4; k < ns0; k += 4) {
        const int ik = beg0 + 8 * k + g;
        unsigned c0 = (unsigned)colidx[ik]      + poff;
        unsigned c1 = (unsigned)colidx[ik + 8]  + poff;
        unsigned c2 = (unsigned)colidx[ik + 16] + poff;
        unsigned c3 = (unsigned)colidx[ik + 24] + poff;
        const int kb = 8 * k;
        uint4 u0 = *reinterpret_cast<const uint4*>(hsb + ((kb      < t0) ? c0 : dumo));
        uint4 u1 = *reinterpret_cast<const uint4*>(hsb + ((kb + 8  < t0) ? c1 : dumo));
        uint4 u2 = *reinterpret_cast<const uint4*>(hsb + ((kb + 16 < t0) ? c2 : dumo));
        uint4 u3 = *reinterpret_cast<const uint4*>(hsb + ((kb + 24 < t0) ? c3 : dumo));
        dotu4(acc0, u0, pl, ph);
        dotu4(acc0, u1, pl, ph);
        dotu4(acc0, u2, pl, ph);
        dotu4(acc0, u3, pl, ph);
    }
    const int ns1 = (deg1 + 7) >> 3;
    for (int k = 4; k < ns1; k += 4) {
        const int ik = beg1 + 8 * k + g;
        unsigned c0 = (unsigned)colidx[ik]      + poff;
        unsigned c1 = (unsigned)colidx[ik + 8]  + poff;
        unsigned c2 = (unsigned)colidx[ik + 16] + poff;
        unsigned c3 = (unsigned)colidx[ik + 24] + poff;
        const int kb = 8 * k;
        uint4 u0 = *reinterpret_cast<const uint4*>(hsb + ((kb      < t1) ? c0 : dumo));
        uint4 u1 = *reinterpret_cast<const uint4*>(hsb + ((kb + 8  < t1) ? c1 : dumo));
        uint4 u2 = *reinterpret_cast<const uint4*>(hsb + ((kb + 16 < t1) ? c2 : dumo));
        uint4 u3 = *reinterpret_cast<const uint4*>(hsb + ((kb + 24 < t1) ? c3 : dumo));
        dotu4(acc1, u0, pl, ph);
        dotu4(acc1, u1, pl, ph);
        dotu4(acc1, u2, pl, ph);
        dotu4(acc1, u3, pl, ph);
    }
    fold8(acc0);
    fold8(acc1);
}

// conv1 aggregation: out16 = fp16(relu(di*(sum_e hs[src_e] + hs_i) + b)).
// 2 nodes per wave; epilogue once: lanes 0-7 -> node0, lanes 8-15 -> node1.
__global__ __launch_bounds__(256) void k_agg_relu(const __half* __restrict__ hs,
                                                  const int* __restrict__ rowptr,
                                                  const int* __restrict__ colidx,
                                                  const float* __restrict__ dinv,
                                                  const float* __restrict__ b,
                                                  __half* __restrict__ out, int n) {
    const int wv = threadIdx.x >> 6;
    const int i0 = blockIdx.x * 8 + wv * 2;
    const int lane = threadIdx.x & 63;
    if (i0 >= n) return;
    const int i1 = min(i0 + 1, n - 1);
    const int g = lane >> 3, p = lane & 7;
    const int iw = (lane & 8) ? i1 : i0;
    const unsigned pk0 = (unsigned)rowptr[i0];
    const unsigned pk1 = (unsigned)rowptr[i1];
    uint4 su = *reinterpret_cast<const uint4*>(hs + ((size_t)iw << 6) + (p << 3));
    const float di = dinv[iw];
    float acc0[8] = {}, acc1[8] = {};
    gather_pair((const char*)hs, colidx, pk0, pk1, g, p, (unsigned)n << 7,
                acc0, acc1);
    if (lane < 16) {
        const f16x2 pl = {(_Float16)1.0f, (_Float16)0.0f};
        const f16x2 ph = {(_Float16)0.0f, (_Float16)1.0f};
        float a[8];
#pragma unroll
        for (int j = 0; j < 8; ++j) a[j] = (lane & 8) ? acc1[j] : acc0[j];
        dotu4(a, su, pl, ph);
        float4 b0 = *reinterpret_cast<const float4*>(b + (p << 3));
        float4 b1 = *reinterpret_cast<const float4*>(b + (p << 3) + 4);
        __half2 h0 = __halves2half2(__float2half(fmaxf(fmaf(a[0], di, b0.x), 0.f)),
                                    __float2half(fmaxf(fmaf(a[1], di, b0.y), 0.f)));
        __half2 h1 = __halves2half2(__float2half(fmaxf(fmaf(a[2], di, b0.z), 0.f)),
                                    __float2half(fmaxf(fmaf(a[3], di, b0.w), 0.f)));
        __half2 h2 = __halves2half2(__float2half(fmaxf(fmaf(a[4], di, b1.x), 0.f)),
                                    __float2half(fmaxf(fmaf(a[5], di, b1.y), 0.f)));
        __half2 h3 = __halves2half2(__float2half(fmaxf(fmaf(a[6], di, b1.z), 0.f)),
                                    __float2half(fmaxf(fmaf(a[7], di, b1.w), 0.f)));
        uint4 u;
        u.x = *reinterpret_cast<unsigned*>(&h0);
        u.y = *reinterpret_cast<unsigned*>(&h1);
        u.z = *reinterpret_cast<unsigned*>(&h2);
        u.w = *reinterpret_cast<unsigned*>(&h3);
        if (iw < n && (i0 + 1 < n || !(lane & 8)))
            *reinterpret_cast<uint4*>(out + ((size_t)iw << 6) + (p << 3)) = u;
    }
}

// conv2 aggregation + relu + (.@Wl + bl) head, fused. 2 nodes per wave;
// xor-1,2,4 reduce stays within each 8-lane group -> lane0 holds v(node0),
// lane8 holds v(node1).
__global__ __launch_bounds__(256) void k_agg_head(const __half* __restrict__ hs,
                                                  const int* __restrict__ rowptr,
                                                  const int* __restrict__ colidx,
                                                  const float* __restrict__ dinv,
                                                  const float* __restrict__ b2,
                                                  const float* __restrict__ Wl,
                                                  const float* __restrict__ bl,
                                                  float* __restrict__ out, int n) {
    const int wv = threadIdx.x >> 6;
    const int i0 = blockIdx.x * 8 + wv * 2;
    const int lane = threadIdx.x & 63;
    if (i0 >= n) return;
    const int i1 = min(i0 + 1, n - 1);
    const int g = lane >> 3, p = lane & 7;
    const int iw = (lane & 8) ? i1 : i0;
    const unsigned pk0 = (unsigned)rowptr[i0];
    const unsigned pk1 = (unsigned)rowptr[i1];
    uint4 su = *reinterpret_cast<const uint4*>(hs + ((size_t)iw << 6) + (p << 3));
    const float di = dinv[iw];
    float acc0[8] = {}, acc1[8] = {};
    gather_pair((const char*)hs, colidx, pk0, pk1, g, p, (unsigned)n << 7,
                acc0, acc1);
    const f16x2 pl = {(_Float16)1.0f, (_Float16)0.0f};
    const f16x2 ph = {(_Float16)0.0f, (_Float16)1.0f};
    float a[8];
#pragma unroll
    for (int j = 0; j < 8; ++j) a[j] = (lane & 8) ? acc1[j] : acc0[j];
    dotu4(a, su, pl, ph);
    float4 b0 = *reinterpret_cast<const float4*>(b2 + (p << 3));
    float4 b1 = *reinterpret_cast<const float4*>(b2 + (p << 3) + 4);
    float4 w0 = *reinterpret_cast<const float4*>(Wl + (p << 3));
    float4 w1 = *reinterpret_cast<const float4*>(Wl + (p << 3) + 4);
    float v = fmaxf(fmaf(a[0], di, b0.x), 0.f) * w0.x
            + fmaxf(fmaf(a[1], di, b0.y), 0.f) * w0.y
            + fmaxf(fmaf(a[2], di, b0.z), 0.f) * w0.z
            + fmaxf(fmaf(a[3], di, b0.w), 0.f) * w0.w
            + fmaxf(fmaf(a[4], di, b1.x), 0.f) * w1.x
            + fmaxf(fmaf(a[5], di, b1.y), 0.f) * w1.y
            + fmaxf(fmaf(a[6], di, b1.z), 0.f) * w1.z
            + fmaxf(fmaf(a[7], di, b1.w), 0.f) * w1.w;
    v += __shfl_xor(v, 1, 64);
    v += __shfl_xor(v, 2, 64);
    v += __shfl_xor(v, 4, 64);
    if (lane == 0) out[i0] = v + bl[0];
    if (lane == 8 && i0 + 1 < n) out[i1] = v + bl[0];
}

extern "C" void kernel_launch(void* const* d_in, const int* in_sizes, int n_in,
                              void* d_out, int out_size, void* d_ws, size_t ws_size,
                              hipStream_t stream) {
    const float* x  = (const float*)d_in[0];
    const int*   ei = (const int*)d_in[1];
    const float* W1 = (const float*)d_in[2];
    const float* b1 = (const float*)d_in[3];
    const float* W2 = (const float*)d_in[4];
    const float* b2 = (const float*)d_in[5];
    const float* Wl = (const float*)d_in[6];
    const float* bl = (const float*)d_in[7];
    float* out = (float*)d_out;

    const int n = in_sizes[0] / 128;   // 100000
    const int E = in_sizes[1] / 2;     // 1600000
    const int* src = ei;
    const int* dst = ei + E;
    const int nb = (n + BSZ - 1) >> SHIFT;          // 196 buckets
    const int nblk = (E + BIN_CH - 1) / BIN_CH;     // 1563 k_bin blocks

    char* ws = (char*)d_ws;
    size_t o = 0;
    auto alloc = [&](size_t bytes) {
        void* p = ws + o;
        o = (o + bytes + 255) & ~(size_t)255;
        return p;
    };
    float* dinv    = (float*)alloc((size_t)n * 4);
    int*   rowptr  = (int*)  alloc((size_t)(n + 1) * 4);
    int*   colidx  = (int*)  alloc(((size_t)E + 64) * 4);        // +slack for unrolled reads
    int*   gbase   = (int*)  alloc((size_t)nblk * (nb + 1) * 4); // per-block bucket offsets
    __half* hs     = (__half*)alloc((size_t)(n + 1) * 64 * 2);   // +1 zeroed dummy row
    __half* bufA   = (__half*)alloc((size_t)n * 64 * 2);         // fp16 relu output
    unsigned* binned = (unsigned*)alloc(((size_t)nblk * BIN_CH) * 4);  // block-major

    // ---- CSR build (block-private counting sort; no memset, no global cursors)
    k_bin<<<nblk, 256, 0, stream>>>(src, dst, binned, gbase, hs, n, nb, E);
    k_bfill<<<nb, 256, 0, stream>>>(binned, gbase, nblk, nb, rowptr, colidx,
                                    dinv, n);

    // ---- conv1 ----
    k_gemm_mfma<128, true><<<(n + 63) / 64, 256, 0, stream>>>(x, W1, dinv, hs, n);
    k_agg_relu<<<(n + 7) / 8, 256, 0, stream>>>(hs, rowptr, colidx, dinv, b1, bufA, n);

    // ---- conv2 + head ----
    k_gemm_mfma<64, false><<<(n + 63) / 64, 256, 0, stream>>>(bufA, W2, dinv, hs, n);
    k_agg_head<<<(n + 7) / 8, 256, 0, stream>>>(hs, rowptr, colidx, dinv, b2, Wl, bl,
                                                out, n);
}